// Round 1
// baseline (452.668 us; speedup 1.0000x reference)
//
#include <hip/hip_runtime.h>

// DeformationGrid: trilinear interpolation of a 160x160x160x3 float32 grid
// at 4,194,304 float32 3D points in the unit cube.
//
// Layout: grid[x][y][z][c] row-major -> index ((x*160 + y)*160 + z)*3 + c.
// The z-pair + channel corners (z, z+1, c=0..2) are 6 contiguous floats.

#define DIM 160
#define STRIDE_X (DIM * DIM * 3)   // 76800
#define STRIDE_Y (DIM * 3)         // 480

__global__ __launch_bounds__(256) void trilerp_kernel(
    const float* __restrict__ coords,
    const float* __restrict__ grid,
    float* __restrict__ out,
    int n)
{
    int i = blockIdx.x * blockDim.x + threadIdx.x;
    if (i >= n) return;

    // coords for this point: 3 contiguous floats (compiler merges loads)
    float cx = coords[3 * i + 0];
    float cy = coords[3 * i + 1];
    float cz = coords[3 * i + 2];

    const float s = (float)(DIM - 1);   // 159
    float px = cx * s, py = cy * s, pz = cz * s;
    float fx = floorf(px), fy = floorf(py), fz = floorf(pz);
    float wx1 = px - fx, wy1 = py - fy, wz1 = pz - fz;
    float wx0 = 1.0f - wx1, wy0 = 1.0f - wy1, wz0 = 1.0f - wz1;

    int ix0 = (int)fx, iy0 = (int)fy, iz0 = (int)fz;
    int ix1 = ix0 + 1, iy1 = iy0 + 1, iz1 = iz0 + 1;

    // Reference semantics: a corner with any out-of-range axis contributes 0
    // (cval=0). valid = AND over axes and w = prod over axes, so zeroing the
    // per-axis weight of an out-of-range index is equivalent; clamp the index
    // so the (weight-0) gather stays in bounds.
    if (ix0 < 0 || ix0 >= DIM) { wx0 = 0.0f; ix0 = ix0 < 0 ? 0 : DIM - 1; }
    if (ix1 < 0 || ix1 >= DIM) { wx1 = 0.0f; ix1 = ix1 < 0 ? 0 : DIM - 1; }
    if (iy0 < 0 || iy0 >= DIM) { wy0 = 0.0f; iy0 = iy0 < 0 ? 0 : DIM - 1; }
    if (iy1 < 0 || iy1 >= DIM) { wy1 = 0.0f; iy1 = iy1 < 0 ? 0 : DIM - 1; }
    if (iz0 < 0 || iz0 >= DIM) { wz0 = 0.0f; iz0 = iz0 < 0 ? 0 : DIM - 1; }
    if (iz1 < 0 || iz1 >= DIM) { wz1 = 0.0f; iz1 = iz1 < 0 ? 0 : DIM - 1; }

    int bx0 = ix0 * STRIDE_X, bx1 = ix1 * STRIDE_X;
    int by0 = iy0 * STRIDE_Y, by1 = iy1 * STRIDE_Y;
    int bz0 = iz0 * 3,        bz1 = iz1 * 3;

    float o0 = 0.0f, o1 = 0.0f, o2 = 0.0f;

    // 4 (x,y) corners; each gathers the contiguous z-pair (6 floats)
    {
        int b = bx0 + by0;
        float w00 = wx0 * wy0;
        const float* g0 = grid + b + bz0;
        const float* g1 = grid + b + bz1;
        float wa = w00 * wz0, wb = w00 * wz1;
        o0 += wa * g0[0] + wb * g1[0];
        o1 += wa * g0[1] + wb * g1[1];
        o2 += wa * g0[2] + wb * g1[2];
    }
    {
        int b = bx0 + by1;
        float w01 = wx0 * wy1;
        const float* g0 = grid + b + bz0;
        const float* g1 = grid + b + bz1;
        float wa = w01 * wz0, wb = w01 * wz1;
        o0 += wa * g0[0] + wb * g1[0];
        o1 += wa * g0[1] + wb * g1[1];
        o2 += wa * g0[2] + wb * g1[2];
    }
    {
        int b = bx1 + by0;
        float w10 = wx1 * wy0;
        const float* g0 = grid + b + bz0;
        const float* g1 = grid + b + bz1;
        float wa = w10 * wz0, wb = w10 * wz1;
        o0 += wa * g0[0] + wb * g1[0];
        o1 += wa * g0[1] + wb * g1[1];
        o2 += wa * g0[2] + wb * g1[2];
    }
    {
        int b = bx1 + by1;
        float w11 = wx1 * wy1;
        const float* g0 = grid + b + bz0;
        const float* g1 = grid + b + bz1;
        float wa = w11 * wz0, wb = w11 * wz1;
        o0 += wa * g0[0] + wb * g1[0];
        o1 += wa * g0[1] + wb * g1[1];
        o2 += wa * g0[2] + wb * g1[2];
    }

    out[3 * i + 0] = o0;
    out[3 * i + 1] = o1;
    out[3 * i + 2] = o2;
}

extern "C" void kernel_launch(void* const* d_in, const int* in_sizes, int n_in,
                              void* d_out, int out_size, void* d_ws, size_t ws_size,
                              hipStream_t stream) {
    const float* coords = (const float*)d_in[0];   // (N_POINTS, 3) f32
    const float* grid   = (const float*)d_in[1];   // (160,160,160,3) f32
    float* out          = (float*)d_out;           // (N_POINTS, 3) f32

    int n = in_sizes[0] / 3;                       // 4,194,304 points
    int block = 256;
    int grid_sz = (n + block - 1) / block;
    trilerp_kernel<<<grid_sz, block, 0, stream>>>(coords, grid, out, n);
}

// Round 2
// 244.818 us; speedup vs baseline: 1.8490x; 1.8490x over previous
//
#include <hip/hip_runtime.h>
#include <hip/hip_fp16.h>

// DeformationGrid: trilinear interp of a 160^3 x3 f32 grid at 4.19M random points.
//
// R1 analysis: bound by random-line fetch beyond L2 (FETCH 1.29 GB @ 3.7 TB/s,
// VALUBusy 4%). 4 scattered (x,y) corner reads/point x ~1.36 lines each.
// R2: per-launch repack into a gather-friendly record: for each cell (x,y,z),
// store the 2x2 xy-corners x 3ch as 12 fp16, padded to 32 B. A point reads
// records (x0,y0,z0) and (x0,y0,z0+1) = one contiguous 64 B (32-aligned)
// => ~1.5 lines/point instead of ~5.4. Footprint 131 MB (L3-resident).

#define DIM 160
#define NCELLS (DIM * DIM * DIM)          // 4,096,000
#define REC_UINTS 8                        // 32 B per record
#define PACKED_BYTES ((size_t)NCELLS * 32) // 131,072,000 B

__device__ __forceinline__ unsigned pack2(float a, float b) {
    unsigned ua = (unsigned)__half_as_ushort(__float2half(a));
    unsigned ub = (unsigned)__half_as_ushort(__float2half(b));
    return ua | (ub << 16);
}
__device__ __forceinline__ float ulo(unsigned u) {
    return __half2float(__ushort_as_half((unsigned short)(u & 0xffffu)));
}
__device__ __forceinline__ float uhi(unsigned u) {
    return __half2float(__ushort_as_half((unsigned short)(u >> 16)));
}

// ---- build: one thread per cell (x,y,z); z fastest for coalescing ----
__global__ __launch_bounds__(256) void build_packed(
    const float* __restrict__ g, uint4* __restrict__ packed)
{
    int t = blockIdx.x * 256 + threadIdx.x;
    if (t >= NCELLS) return;
    int z  = t % DIM;
    int xy = t / DIM;
    int y  = xy % DIM;
    int x  = xy / DIM;
    int xp = x < DIM - 1 ? x + 1 : DIM - 1;
    int yp = y < DIM - 1 ? y + 1 : DIM - 1;

    const float* p00 = g + (((size_t)x  * DIM + y ) * DIM + z) * 3;
    const float* p10 = g + (((size_t)xp * DIM + y ) * DIM + z) * 3;
    const float* p01 = g + (((size_t)x  * DIM + yp) * DIM + z) * 3;
    const float* p11 = g + (((size_t)xp * DIM + yp) * DIM + z) * 3;

    float a0 = p00[0], a1 = p00[1], a2 = p00[2];
    float b0 = p10[0], b1 = p10[1], b2 = p10[2];
    float c0 = p01[0], c1 = p01[1], c2 = p01[2];
    float d0 = p11[0], d1 = p11[1], d2 = p11[2];

    // record halves: [c00.xyz, c10.xyz, c01.xyz, c11.xyz, pad x4]
    uint4 w0, w1;
    w0.x = pack2(a0, a1);
    w0.y = pack2(a2, b0);
    w0.z = pack2(b1, b2);
    w0.w = pack2(c0, c1);
    w1.x = pack2(c2, d0);
    w1.y = pack2(d1, d2);
    w1.z = 0u;
    w1.w = 0u;

    uint4* dst = packed + (size_t)t * 2;
    dst[0] = w0;
    dst[1] = w1;
}

// ---- gather: one thread per point, one 64 B contiguous read ----
__global__ __launch_bounds__(256) void trilerp_packed(
    const float* __restrict__ coords,
    const uint4* __restrict__ packed,
    float* __restrict__ out,
    int n)
{
    int i = blockIdx.x * 256 + threadIdx.x;
    if (i >= n) return;

    float cx = coords[3 * i + 0];
    float cy = coords[3 * i + 1];
    float cz = coords[3 * i + 2];

    const float s = (float)(DIM - 1);
    float px = cx * s, py = cy * s, pz = cz * s;
    float fx = floorf(px), fy = floorf(py), fz = floorf(pz);
    float wx1 = px - fx, wy1 = py - fy, wz1 = pz - fz;
    float wx0 = 1.0f - wx1, wy0 = 1.0f - wy1, wz0 = 1.0f - wz1;

    // coords in [0,1) => px in [0,159): indices always in range; defensive clamp
    int x0 = min(max((int)fx, 0), DIM - 2);
    int y0 = min(max((int)fy, 0), DIM - 2);
    int z0 = min(max((int)fz, 0), DIM - 2);

    float w00 = wx0 * wy0, w10 = wx1 * wy0, w01 = wx0 * wy1, w11 = wx1 * wy1;

    const uint4* p = packed + ((size_t)((x0 * DIM + y0) * DIM + z0)) * 2;
    uint4 A = p[0];   // z0: c00(xyz) c10(xy)
    uint4 B = p[1];   // z0: c10(z) is in A.z... layout per build: see unpack
    uint4 C = p[2];   // z1 record
    uint4 D = p[3];

    float o0, o1, o2;
    {   // z0 plane, weight wz0
        float wA = w00 * wz0, wB = w10 * wz0, wC = w01 * wz0, wD = w11 * wz0;
        o0 = wA * ulo(A.x) + wB * uhi(A.y) + wC * ulo(A.w) + wD * uhi(B.x);
        o1 = wA * uhi(A.x) + wB * ulo(A.z) + wC * uhi(A.w) + wD * ulo(B.y);
        o2 = wA * ulo(A.y) + wB * uhi(A.z) + wC * ulo(B.x) + wD * uhi(B.y);
    }
    {   // z1 plane, weight wz1
        float wA = w00 * wz1, wB = w10 * wz1, wC = w01 * wz1, wD = w11 * wz1;
        o0 += wA * ulo(C.x) + wB * uhi(C.y) + wC * ulo(C.w) + wD * uhi(D.x);
        o1 += wA * uhi(C.x) + wB * ulo(C.z) + wC * uhi(C.w) + wD * ulo(D.y);
        o2 += wA * ulo(C.y) + wB * uhi(C.z) + wC * ulo(D.x) + wD * uhi(D.y);
    }

    out[3 * i + 0] = o0;
    out[3 * i + 1] = o1;
    out[3 * i + 2] = o2;
}

// ---- fallback (R1 kernel) if workspace is too small ----
#define STRIDE_X (DIM * DIM * 3)
#define STRIDE_Y (DIM * 3)
__global__ __launch_bounds__(256) void trilerp_direct(
    const float* __restrict__ coords,
    const float* __restrict__ grid,
    float* __restrict__ out,
    int n)
{
    int i = blockIdx.x * blockDim.x + threadIdx.x;
    if (i >= n) return;
    float cx = coords[3 * i + 0], cy = coords[3 * i + 1], cz = coords[3 * i + 2];
    const float s = (float)(DIM - 1);
    float px = cx * s, py = cy * s, pz = cz * s;
    float fx = floorf(px), fy = floorf(py), fz = floorf(pz);
    float wx1 = px - fx, wy1 = py - fy, wz1 = pz - fz;
    float wx0 = 1.0f - wx1, wy0 = 1.0f - wy1, wz0 = 1.0f - wz1;
    int x0 = min(max((int)fx, 0), DIM - 2);
    int y0 = min(max((int)fy, 0), DIM - 2);
    int z0 = min(max((int)fz, 0), DIM - 2);
    int bx0 = x0 * STRIDE_X, bx1 = bx0 + STRIDE_X;
    int by0 = y0 * STRIDE_Y, by1 = by0 + STRIDE_Y;
    int bz0 = z0 * 3;
    float o0 = 0, o1 = 0, o2 = 0;
    {
        const float* g0 = grid + bx0 + by0 + bz0;
        float wa = wx0 * wy0 * wz0, wb = wx0 * wy0 * wz1;
        o0 += wa * g0[0] + wb * g0[3]; o1 += wa * g0[1] + wb * g0[4]; o2 += wa * g0[2] + wb * g0[5];
    }
    {
        const float* g0 = grid + bx0 + by1 + bz0;
        float wa = wx0 * wy1 * wz0, wb = wx0 * wy1 * wz1;
        o0 += wa * g0[0] + wb * g0[3]; o1 += wa * g0[1] + wb * g0[4]; o2 += wa * g0[2] + wb * g0[5];
    }
    {
        const float* g0 = grid + bx1 + by0 + bz0;
        float wa = wx1 * wy0 * wz0, wb = wx1 * wy0 * wz1;
        o0 += wa * g0[0] + wb * g0[3]; o1 += wa * g0[1] + wb * g0[4]; o2 += wa * g0[2] + wb * g0[5];
    }
    {
        const float* g0 = grid + bx1 + by1 + bz0;
        float wa = wx1 * wy1 * wz0, wb = wx1 * wy1 * wz1;
        o0 += wa * g0[0] + wb * g0[3]; o1 += wa * g0[1] + wb * g0[4]; o2 += wa * g0[2] + wb * g0[5];
    }
    out[3 * i + 0] = o0; out[3 * i + 1] = o1; out[3 * i + 2] = o2;
}

extern "C" void kernel_launch(void* const* d_in, const int* in_sizes, int n_in,
                              void* d_out, int out_size, void* d_ws, size_t ws_size,
                              hipStream_t stream) {
    const float* coords = (const float*)d_in[0];   // (N, 3) f32
    const float* grid   = (const float*)d_in[1];   // (160,160,160,3) f32
    float* out          = (float*)d_out;           // (N, 3) f32
    int n = in_sizes[0] / 3;

    if (ws_size >= PACKED_BYTES) {
        uint4* packed = (uint4*)d_ws;
        build_packed<<<NCELLS / 256, 256, 0, stream>>>(grid, packed);
        trilerp_packed<<<(n + 255) / 256, 256, 0, stream>>>(coords, packed, out, n);
    } else {
        trilerp_direct<<<(n + 255) / 256, 256, 0, stream>>>(coords, grid, out, n);
    }
}